// Round 1
// baseline (331.233 us; speedup 1.0000x reference)
//
#include <hip/hip_runtime.h>
#include <stdint.h>

// ---------------------------------------------------------------------------
// LocalAtomAttention on gfx950.
//   x:[16,4096,4,128] f32, mask:[16,4096,4] int, Wq/bq/Wk/bk/Wv/bv/Wo/bo.
//   Fused: QKV proj (bf16 MFMA) -> per-residue 4x4x4head attention -> out proj.
// Design:
//   - pre-kernel converts W* to bf16 in d_ws (L2-resident, reused by all blocks)
//   - main: 4096 blocks x 256 thr, 16 residues (64 rows)/block
//   - A-frags (x) from global fp32 + in-reg pack; B-frags (W) from global bf16
//   - LDS only for Q/K/V/O (4 x 16KB = 64KB exact -> 2 blocks/CU), 2 barriers
// ---------------------------------------------------------------------------

typedef __bf16 bf16x8 __attribute__((ext_vector_type(8)));
typedef float  f32x4  __attribute__((ext_vector_type(4)));

#define N_RES 65536   // B*L = 16*4096
#define RPB   16      // residues per block
#define MROWS 64      // RPB*4 atom rows
#define CDIM  128

// round-half-up f32->bf16 pair pack (2 adds + perm-able or/shr; near-RNE)
__device__ __forceinline__ uint32_t pk2(float a, float b) {
    uint32_t ua = __builtin_bit_cast(uint32_t, a) + 0x8000u;
    uint32_t ub = __builtin_bit_cast(uint32_t, b) + 0x8000u;
    return (ua >> 16) | (ub & 0xffff0000u);
}
// exact RNE f32->bf16 (used where cheap)
__device__ __forceinline__ uint16_t f2bf(float a) {
    uint32_t u = __builtin_bit_cast(uint32_t, a);
    return (uint16_t)((u + 0x7fffu + ((u >> 16) & 1u)) >> 16);
}
__device__ __forceinline__ bf16x8 pack8(float4 f0, float4 f1) {
    uint4 uu = make_uint4(pk2(f0.x, f0.y), pk2(f0.z, f0.w),
                          pk2(f1.x, f1.y), pk2(f1.z, f1.w));
    return __builtin_bit_cast(bf16x8, uu);
}
__device__ __forceinline__ void bf8_unpack(uint4 u, float* f) {
    f[0] = __builtin_bit_cast(float, u.x << 16);
    f[1] = __builtin_bit_cast(float, u.x & 0xffff0000u);
    f[2] = __builtin_bit_cast(float, u.y << 16);
    f[3] = __builtin_bit_cast(float, u.y & 0xffff0000u);
    f[4] = __builtin_bit_cast(float, u.z << 16);
    f[5] = __builtin_bit_cast(float, u.z & 0xffff0000u);
    f[6] = __builtin_bit_cast(float, u.w << 16);
    f[7] = __builtin_bit_cast(float, u.w & 0xffff0000u);
}

// --------------------------- W fp32 -> bf16 pre-pass ------------------------
__global__ void wconv_kernel(const float* __restrict__ wq, const float* __restrict__ wk,
                             const float* __restrict__ wv, const float* __restrict__ wo,
                             uint16_t* __restrict__ dst) {
    int i = blockIdx.x * 256 + threadIdx.x;          // 65536 threads total
    const float* s = (i < 16384) ? wq : (i < 32768) ? wk : (i < 49152) ? wv : wo;
    dst[i] = f2bf(s[i & 16383]);
}

// --------------------------------- main -------------------------------------
template <bool USEWS>
__global__ __launch_bounds__(256, 2)
void laa_main(const float* __restrict__ x, const int* __restrict__ mask,
              const float* __restrict__ Wq, const float* __restrict__ bq,
              const float* __restrict__ Wk, const float* __restrict__ bk,
              const float* __restrict__ Wv, const float* __restrict__ bv,
              const float* __restrict__ Wo, const float* __restrict__ bo,
              const uint16_t* __restrict__ wbf,
              float* __restrict__ out) {
    __shared__ uint16_t sQ[MROWS * CDIM];
    __shared__ uint16_t sK[MROWS * CDIM];
    __shared__ uint16_t sV[MROWS * CDIM];
    __shared__ uint16_t sO[MROWS * CDIM];

    const int tid  = threadIdx.x;
    const int wave = tid >> 6;        // 0..3 -> owns output cols [wave*32, wave*32+32)
    const int lane = tid & 63;
    const int lrow = lane & 15;
    const int quad = lane >> 4;
    const long m0  = (long)blockIdx.x * MROWS;   // global atom-row base

    const f32x4 vzero = {0.f, 0.f, 0.f, 0.f};

    // ---- A-fragments: whole 64x128 x-tile, fp32 global -> bf16 regs --------
    bf16x8 af[4][4];   // [m-tile][k-step]
    {
        const float* xb = x + m0 * CDIM;
        #pragma unroll
        for (int m = 0; m < 4; ++m) {
            const float* rowp = xb + (m * 16 + lrow) * CDIM;
            #pragma unroll
            for (int ks = 0; ks < 4; ++ks) {
                const float4* p = (const float4*)(rowp + ks * 32 + quad * 8);
                af[m][ks] = pack8(p[0], p[1]);
            }
        }
    }

    // ---- fused Q/K/V GEMMs (N-split across waves) --------------------------
    f32x4 acc[3][4][2];  // [qkv][m-tile][n-tile]
    #pragma unroll
    for (int g = 0; g < 3; ++g)
        #pragma unroll
        for (int m = 0; m < 4; ++m)
            #pragma unroll
            for (int nt = 0; nt < 2; ++nt) acc[g][m][nt] = vzero;

    const float* wsrc32[3] = {Wq, Wk, Wv};
    #pragma unroll
    for (int ks = 0; ks < 4; ++ks) {
        bf16x8 bfr[3][2];
        #pragma unroll
        for (int g = 0; g < 3; ++g) {
            #pragma unroll
            for (int nt = 0; nt < 2; ++nt) {
                int wrow = wave * 32 + nt * 16 + lrow;   // output channel (row of W)
                if constexpr (USEWS) {
                    bfr[g][nt] = *(const bf16x8*)(wbf + g * 16384 + wrow * CDIM + ks * 32 + quad * 8);
                } else {
                    const float* wp = wsrc32[g] + wrow * CDIM + ks * 32 + quad * 8;
                    bfr[g][nt] = pack8(((const float4*)wp)[0], ((const float4*)wp)[1]);
                }
            }
        }
        #pragma unroll
        for (int g = 0; g < 3; ++g)
            #pragma unroll
            for (int m = 0; m < 4; ++m)
                #pragma unroll
                for (int nt = 0; nt < 2; ++nt)
                    acc[g][m][nt] = __builtin_amdgcn_mfma_f32_16x16x32_bf16(
                        af[m][ks], bfr[g][nt], acc[g][m][nt], 0, 0, 0);
    }

    // ---- epilogue: +bias, bf16, scatter to LDS (C-layout) ------------------
    {
        uint16_t* sdst[3] = {sQ, sK, sV};
        const float* bias[3] = {bq, bk, bv};
        #pragma unroll
        for (int g = 0; g < 3; ++g) {
            #pragma unroll
            for (int nt = 0; nt < 2; ++nt) {
                int col = wave * 32 + nt * 16 + lrow;
                float bb = bias[g][col];
                #pragma unroll
                for (int m = 0; m < 4; ++m) {
                    #pragma unroll
                    for (int r = 0; r < 4; ++r) {
                        int row = m * 16 + quad * 4 + r;
                        sdst[g][row * CDIM + col] = f2bf(acc[g][m][nt][r] + bb);
                    }
                }
            }
        }
    }
    __syncthreads();

    // ---- attention: 1 thread per (residue, head, q_atom) -------------------
    {
        const int rl = tid >> 4;          // local residue 0..15
        const int h  = (tid >> 2) & 3;    // head
        const int qa = tid & 3;           // query atom
        const int rowq = rl * 4 + qa;
        const int cb = h * 32;

        const int4 mk = *(const int4*)(mask + ((long)blockIdx.x * RPB + rl) * 4);
        const int mka[4] = {mk.x, mk.y, mk.z, mk.w};

        float qv[32];
        {
            const uint4* qp = (const uint4*)(sQ + rowq * CDIM + cb);
            #pragma unroll
            for (int c = 0; c < 4; ++c) bf8_unpack(qp[c], qv + c * 8);
        }
        float sc[4];
        #pragma unroll
        for (int ka = 0; ka < 4; ++ka) {
            const uint4* kp = (const uint4*)(sK + (rl * 4 + ka) * CDIM + cb);
            float d = 0.f;
            #pragma unroll
            for (int c = 0; c < 4; ++c) {
                float kv[8]; bf8_unpack(kp[c], kv);
                #pragma unroll
                for (int j = 0; j < 8; ++j) d += qv[c * 8 + j] * kv[j];
            }
            sc[ka] = d * 0.17677669529663689f;   // 1/sqrt(32)
        }
        float mx = -3e38f;
        #pragma unroll
        for (int ka = 0; ka < 4; ++ka) if (mka[ka]) mx = fmaxf(mx, sc[ka]);
        float e[4], ssum = 0.f;
        #pragma unroll
        for (int ka = 0; ka < 4; ++ka) {
            e[ka] = mka[ka] ? __expf(sc[ka] - mx) : 0.f;
            ssum += e[ka];
        }
        const float inv = ssum > 0.f ? 1.f / ssum : 0.f;

        float o[32];
        #pragma unroll
        for (int j = 0; j < 32; ++j) o[j] = 0.f;
        #pragma unroll
        for (int ka = 0; ka < 4; ++ka) {
            float wgt = e[ka] * inv;
            const uint4* vp = (const uint4*)(sV + (rl * 4 + ka) * CDIM + cb);
            #pragma unroll
            for (int c = 0; c < 4; ++c) {
                float vv[8]; bf8_unpack(vp[c], vv);
                #pragma unroll
                for (int j = 0; j < 8; ++j) o[c * 8 + j] += wgt * vv[j];
            }
        }
        uint32_t* op = (uint32_t*)(sO + rowq * CDIM + cb);
        #pragma unroll
        for (int c2 = 0; c2 < 16; ++c2) op[c2] = pk2(o[2 * c2], o[2 * c2 + 1]);
    }
    __syncthreads();

    // ---- output projection: out = O @ Wo^T + bo, * residue_mask ------------
    f32x4 acc2[4][2];
    #pragma unroll
    for (int m = 0; m < 4; ++m)
        #pragma unroll
        for (int nt = 0; nt < 2; ++nt) acc2[m][nt] = vzero;

    #pragma unroll
    for (int ks = 0; ks < 4; ++ks) {
        bf16x8 a2[4];
        #pragma unroll
        for (int m = 0; m < 4; ++m)
            a2[m] = *(const bf16x8*)(sO + (m * 16 + lrow) * CDIM + ks * 32 + quad * 8);
        bf16x8 b2[2];
        #pragma unroll
        for (int nt = 0; nt < 2; ++nt) {
            int wrow = wave * 32 + nt * 16 + lrow;
            if constexpr (USEWS) {
                b2[nt] = *(const bf16x8*)(wbf + 3 * 16384 + wrow * CDIM + ks * 32 + quad * 8);
            } else {
                const float* wp = Wo + wrow * CDIM + ks * 32 + quad * 8;
                b2[nt] = pack8(((const float4*)wp)[0], ((const float4*)wp)[1]);
            }
        }
        #pragma unroll
        for (int m = 0; m < 4; ++m)
            #pragma unroll
            for (int nt = 0; nt < 2; ++nt)
                acc2[m][nt] = __builtin_amdgcn_mfma_f32_16x16x32_bf16(
                    a2[m], b2[nt], acc2[m][nt], 0, 0, 0);
    }
    {
        #pragma unroll
        for (int m = 0; m < 4; ++m) {
            // rows m*16+quad*4+r (r=0..3) all belong to local residue m*4+quad
            const int4 mk2 = *(const int4*)(mask + ((long)blockIdx.x * RPB + m * 4 + quad) * 4);
            const float rm = (mk2.x | mk2.y | mk2.z | mk2.w) ? 1.f : 0.f;
            #pragma unroll
            for (int nt = 0; nt < 2; ++nt) {
                int col = wave * 32 + nt * 16 + lrow;
                float bb = bo[col];
                #pragma unroll
                for (int r = 0; r < 4; ++r) {
                    long row = m0 + m * 16 + quad * 4 + r;
                    out[row * CDIM + col] = (acc2[m][nt][r] + bb) * rm;
                }
            }
        }
    }
}

// ------------------------------- launcher -----------------------------------
extern "C" void kernel_launch(void* const* d_in, const int* in_sizes, int n_in,
                              void* d_out, int out_size, void* d_ws, size_t ws_size,
                              hipStream_t stream) {
    const float* x    = (const float*)d_in[0];
    const int*   mask = (const int*)d_in[1];
    const float* Wq   = (const float*)d_in[2];
    const float* bq   = (const float*)d_in[3];
    const float* Wk   = (const float*)d_in[4];
    const float* bk   = (const float*)d_in[5];
    const float* Wv   = (const float*)d_in[6];
    const float* bv   = (const float*)d_in[7];
    const float* Wo   = (const float*)d_in[8];
    const float* bo   = (const float*)d_in[9];
    float* out = (float*)d_out;

    const int nblocks = N_RES / RPB;   // 4096
    const bool usews = ws_size >= (size_t)(4 * 16384 * sizeof(uint16_t));
    if (usews) {
        uint16_t* wbf = (uint16_t*)d_ws;
        wconv_kernel<<<256, 256, 0, stream>>>(Wq, Wk, Wv, Wo, wbf);
        laa_main<true><<<nblocks, 256, 0, stream>>>(x, mask, Wq, bq, Wk, bk, Wv, bv,
                                                    Wo, bo, wbf, out);
    } else {
        laa_main<false><<<nblocks, 256, 0, stream>>>(x, mask, Wq, bq, Wk, bk, Wv, bv,
                                                     Wo, bo, nullptr, out);
    }
}